// Round 6
// baseline (587.560 us; speedup 1.0000x reference)
//
#include <hip/hip_runtime.h>
#include <cstdint>
#include <cstddef>

// Problem constants
constexpr int cB = 8, cC = 256, cT = 16000, cN = 32;
constexpr int cP = 125;            // chunks per sequence (125*128 = 16000)
constexpr float cEPS = 1e-8f;

typedef __bf16 bf16;
typedef __bf16 bf16x4 __attribute__((ext_vector_type(4)));
typedef __bf16 bf16x8 __attribute__((ext_vector_type(8)));
typedef float floatx4 __attribute__((ext_vector_type(4)));

// Workspace layout (bytes), all 16B-aligned
constexpr size_t kMean = 0;                                // B*T f32
constexpr size_t kRstd = kMean + (size_t)cB * cT * 4;      // B*T f32
constexpr size_t kWlr  = kRstd + (size_t)cB * cT * 4;      // C*32 f32 (w^128 re)
constexpr size_t kWli  = kWlr + (size_t)cC * cN * 4;       // C*32 f32 (w^128 im)
constexpr size_t kWb   = kWli + (size_t)cC * cN * 4;       // 512*256 bf16
constexpr size_t kLt   = kWb  + (size_t)512 * 256 * 2;     // C*128*128 bf16 (Toeplitz, row j: k[j-i])
constexpr size_t kEt   = kLt  + (size_t)cC * 128 * 128 * 2;// C*64*128 bf16 (state extraction)
constexpr size_t kVt   = kEt  + (size_t)cC * 64 * 128 * 2; // C*128*64 bf16 (correction)
constexpr size_t kU    = kVt  + (size_t)cC * 128 * 64 * 2; // B*C*T bf16 (u, [b][c][t])

__device__ __forceinline__ float fast_sigmoid(float z) {
  return __builtin_amdgcn_rcpf(1.f + __builtin_amdgcn_exp2f(-z * 1.4426950408889634f));
}

// ---------------- prepW: W_out -> bf16 ----------------
__global__ void prepW_kernel(const float* __restrict__ W_out, bf16* __restrict__ Wb) {
  int idx = blockIdx.x * 256 + threadIdx.x;
  if (idx < 512 * 256) Wb[idx] = (bf16)W_out[idx];
}

// ---------------- prep2: per-channel S4D matrices (Lt, Et, Vt, w^128) ----------------
__global__ void prep2_kernel(const float* __restrict__ log_dt,
                             const float* __restrict__ log_A_real,
                             const float* __restrict__ A_imag,
                             const float* __restrict__ C_re,
                             const float* __restrict__ C_im,
                             float* __restrict__ wlr, float* __restrict__ wli,
                             bf16* __restrict__ Lt, bf16* __restrict__ Et,
                             bf16* __restrict__ Vt) {
  int c = blockIdx.x;        // 256 blocks
  int j = threadIdx.x;       // 128 threads
  __shared__ float kv[128];
  float dt = expf(log_dt[c]);
  float kj = 0.f;
  for (int n = 0; n < cN; ++n) {
    int idx = c * cN + n;
    float Ar = -expf(log_A_real[idx]);
    float Ai = A_imag[idx];
    float ar = dt * Ar, ai = dt * Ai;           // dtA
    float mg = expf(ar), cw, sw;
    sincosf(ai, &sw, &cw);
    float wre = mg * cw, wim = mg * sw;
    float den = Ar * Ar + Ai * Ai;
    float emr = wre - 1.f, emi = wim;
    float qr = (emr * Ar + emi * Ai) / den;
    float qi = (emi * Ar - emr * Ai) / den;
    float cre = C_re[idx], cim = C_im[idx];
    float c2r = 2.f * (cre * qr - cim * qi);
    float c2i = 2.f * (cre * qi + cim * qr);
    float mj = expf((float)j * ar), cj, sj;
    sincosf((float)j * ai, &sj, &cj);
    float wjr = mj * cj, wji = mj * sj;
    kj += c2r * wjr - c2i * wji;                 // k[j] = Re(Cc2 * w^j)
    float w1r = wjr * wre - wji * wim;
    float w1i = wjr * wim + wji * wre;
    Vt[(size_t)c * 8192 + j * 64 + 2 * n]     = (bf16)(c2r * w1r - c2i * w1i);
    Vt[(size_t)c * 8192 + j * 64 + 2 * n + 1] = (bf16)(-(c2r * w1i + c2i * w1r));
    float mr = expf((float)(127 - j) * ar), cr2, sr2;
    sincosf((float)(127 - j) * ai, &sr2, &cr2);
    Et[(size_t)c * 8192 + (2 * n) * 128 + j]     = (bf16)(mr * cr2);
    Et[(size_t)c * 8192 + (2 * n + 1) * 128 + j] = (bf16)(mr * sr2);
  }
  kv[j] = kj;
  if (j < cN) {      // w^128 for the chunk prefix
    int idx = c * cN + j;
    float Ar = -expf(log_A_real[idx]);
    float ai = dt * A_imag[idx], ar = dt * Ar;
    float m = expf(128.f * ar), cc, ss;
    sincosf(128.f * ai, &ss, &cc);
    wlr[idx] = m * cc;
    wli[idx] = m * ss;
  }
  __syncthreads();
  // Lt[row][col] = k[row-col] for col<=row else 0 — coalesced linear writeout
  bf16* LtC = Lt + (size_t)c * 16384;
  for (int e = j; e < 4096; e += 128) {    // 4096 bf16x4 groups
    int t4 = e * 4;
    int row = t4 >> 7, col = t4 & 127;
    bf16x4 v;
#pragma unroll
    for (int q = 0; q < 4; ++q) {
      int ii = col + q;
      v[q] = (ii <= row) ? (bf16)kv[row - ii] : (bf16)0.f;
    }
    *(bf16x4*)(LtC + row * 128 + col) = v;
  }
}

// ---------------- stats: per-(b,t) mean / rstd over C ----------------
// 1000 blocks x 512 thr; block = 128 tokens, 8 c-groups of 32, float2 loads.
__global__ __launch_bounds__(512)
void stats_kernel(const float* __restrict__ x,
                  float* __restrict__ meanp, float* __restrict__ rstdp) {
  __shared__ float S1[8][128], S2[8][128];
  int g0 = blockIdx.x * 128;                // 128 tokens per block (125 blocks per b)
  int b = g0 / cT;
  int t0 = g0 - b * cT;
  int tp = threadIdx.x & 63, cq = threadIdx.x >> 6;   // tp: token-pair, cq: c-group
  const float2* xp = (const float2*)(x + ((size_t)b * cC + cq * 32) * cT + t0) + tp;
  float s1x = 0.f, s1y = 0.f, s2x = 0.f, s2y = 0.f;
#pragma unroll 8
  for (int cc = 0; cc < 32; ++cc) {
    float2 v = xp[(size_t)cc * (cT / 2)];
    s1x += v.x; s2x = fmaf(v.x, v.x, s2x);
    s1y += v.y; s2y = fmaf(v.y, v.y, s2y);
  }
  S1[cq][2 * tp] = s1x; S1[cq][2 * tp + 1] = s1y;
  S2[cq][2 * tp] = s2x; S2[cq][2 * tp + 1] = s2y;
  __syncthreads();
  if (threadIdx.x < 128) {
    float a1 = 0.f, a2 = 0.f;
#pragma unroll
    for (int q = 0; q < 8; ++q) { a1 += S1[q][threadIdx.x]; a2 += S2[q][threadIdx.x]; }
    float mean = a1 * (1.0f / cC);
    float var = fmaf(a2, 1.0f / cC, -mean * mean);
    int g = g0 + threadIdx.x;
    meanp[g] = mean;
    rstdp[g] = rsqrtf(var + cEPS);
  }
}

// ---------------- scanM: LN+PReLU -> MFMA chunked scan -> skip -> GELU -> U[b][c][t] ----------------
// 512 threads (8 waves), 2 blocks/CU -> 16 waves/CU. XCD-swizzled so the 8 b-siblings
// of one channel land on the same XCD (share Lt/Et/Vt in that XCD's L2).
__global__ __launch_bounds__(512, 4)
void scanM_kernel(const float* __restrict__ x, const float* __restrict__ meanp,
                  const float* __restrict__ rstdp, const float* __restrict__ gam,
                  const float* __restrict__ bet, const float* __restrict__ prw,
                  const float* __restrict__ Dp,
                  const float* __restrict__ wlr, const float* __restrict__ wli,
                  const bf16* __restrict__ Lt, const bf16* __restrict__ Et,
                  const bf16* __restrict__ Vt, bf16* __restrict__ U) {
  __shared__ __align__(16) bf16 Y[128 * 136];
  __shared__ __align__(16) bf16 H[128 * 136];
  __shared__ float Sseg[8][32][2];

  int blk = blockIdx.x;
  // XCD chunk swizzle (2048 % 8 == 0, bijective): consecutive blk round-robin XCDs,
  // logical ids chunk so that one channel's 8 b-siblings share an XCD.
  int logical = (blk & 7) * 256 + (blk >> 3);
  int b = logical & 7, c = logical >> 3;
  int tid = threadIdx.x;
  int lane = tid & 63, w8 = tid >> 6, quad = lane >> 4, mh = lane & 15;
  float gamma = gam[c], beta = bet[c], pw = prw[c], Dc = Dp[c];

  // ---- phase 1: y = PReLU(LN(x)) -> Y LDS (bf16) ----
  const float4* x4 = (const float4*)(x + (size_t)(b * cC + c) * cT);
  const float4* m4 = (const float4*)(meanp + (size_t)b * cT);
  const float4* r4 = (const float4*)(rstdp + (size_t)b * cT);
#pragma unroll
  for (int it = 0; it < 8; ++it) {
    int i4 = tid + it * 512;
    if (i4 < 4000) {
      float4 xv = x4[i4], mv = m4[i4], rv = r4[i4];
      int t = i4 * 4, p = t >> 7, j = t & 127;
      float ys[4];
      ys[0] = fmaf((xv.x - mv.x) * rv.x, gamma, beta);
      ys[1] = fmaf((xv.y - mv.y) * rv.y, gamma, beta);
      ys[2] = fmaf((xv.z - mv.z) * rv.z, gamma, beta);
      ys[3] = fmaf((xv.w - mv.w) * rv.w, gamma, beta);
      bf16x4 yv;
#pragma unroll
      for (int q = 0; q < 4; ++q) {
        float y = ys[q];
        yv[q] = (bf16)(y >= 0.f ? y : y * pw);
      }
      *(bf16x4*)&Y[p * 136 + j] = yv;
    }
  }
  for (int e = tid; e < 3 * 136; e += 512) Y[125 * 136 + e] = (bf16)0.f;  // pad rows
  __syncthreads();

  // ---- phase 2: extraction H[p][comp] = sum_i Y[p][i]*Et[comp][i]; store bf16 hi/lo ----
  // wave w8: comp group = (w8&3)*16, row half = (w8>>2)*4
  const bf16* EtC = Et + (size_t)c * 8192;
  int cgrp = (w8 & 3) * 16, mbase = (w8 >> 2) * 4;
  floatx4 hacc[4];
#pragma unroll
  for (int mi = 0; mi < 4; ++mi) hacc[mi] = (floatx4){0.f, 0.f, 0.f, 0.f};
#pragma unroll
  for (int kk = 0; kk < 4; ++kk) {
    bf16x8 bfrag = *(const bf16x8*)(EtC + (cgrp + mh) * 128 + kk * 32 + quad * 8);
#pragma unroll
    for (int mi = 0; mi < 4; ++mi) {
      bf16x8 af = *(bf16x8*)&Y[((mbase + mi) * 16 + mh) * 136 + kk * 32 + quad * 8];
      hacc[mi] = __builtin_amdgcn_mfma_f32_16x16x32_bf16(af, bfrag, hacc[mi], 0, 0, 0);
    }
  }
#pragma unroll
  for (int mi = 0; mi < 4; ++mi) {
#pragma unroll
    for (int r = 0; r < 4; ++r) {
      int p = (mbase + mi) * 16 + quad * 4 + r;
      int comp = cgrp + mh;
      float v = hacc[mi][r];
      bf16 hi = (bf16)v;
      bf16 lo = (bf16)(v - (float)hi);
      H[p * 136 + comp] = hi;
      H[p * 136 + 64 + comp] = lo;
    }
  }
  __syncthreads();

  // ---- phase 3: segmented prefix over chunks (exclusive), in place (first 256 thr) ----
  {
    int n = tid & 31, sg = (tid >> 5) & 7;
    int p0 = sg * 16;
    int p1 = (p0 + 16 < cP) ? p0 + 16 : cP;
    float wr = wlr[c * cN + n], wi = wli[c * cN + n];
    float hR = 0.f, hI = 0.f;
    if (tid < 256) {
      for (int p = p0; p < p1; ++p) {
        float sr = (float)H[p * 136 + 2 * n] + (float)H[p * 136 + 64 + 2 * n];
        float si = (float)H[p * 136 + 2 * n + 1] + (float)H[p * 136 + 64 + 2 * n + 1];
        float t1 = fmaf(wr, hR, fmaf(-wi, hI, sr));
        hI = fmaf(wr, hI, fmaf(wi, hR, si));
        hR = t1;
      }
      Sseg[sg][n][0] = hR; Sseg[sg][n][1] = hI;
    }
    __syncthreads();
    if (tid < 32) {
      float ar = wr, ai = wi;       // (w^128)^16 via 4 squarings
      for (int q = 0; q < 4; ++q) {
        float nr = ar * ar - ai * ai;
        ai = 2.f * ar * ai; ar = nr;
      }
      float HR = 0.f, HI = 0.f;
      for (int s2 = 0; s2 < 8; ++s2) {
        float fr = Sseg[s2][n][0], fi = Sseg[s2][n][1];
        Sseg[s2][n][0] = HR; Sseg[s2][n][1] = HI;
        float t1 = fmaf(ar, HR, fmaf(-ai, HI, fr));
        HI = fmaf(ar, HI, fmaf(ai, HR, fi));
        HR = t1;
      }
    }
    __syncthreads();
    if (tid < 256) {
      hR = Sseg[sg][n][0]; hI = Sseg[sg][n][1];
      for (int p = p0; p < p1; ++p) {
        float sr = (float)H[p * 136 + 2 * n] + (float)H[p * 136 + 64 + 2 * n];
        float si = (float)H[p * 136 + 2 * n + 1] + (float)H[p * 136 + 64 + 2 * n + 1];
        bf16 hiR = (bf16)hR; bf16 loR = (bf16)(hR - (float)hiR);
        bf16 hiI = (bf16)hI; bf16 loI = (bf16)(hI - (float)hiI);
        H[p * 136 + 2 * n] = hiR;      H[p * 136 + 2 * n + 1] = hiI;
        H[p * 136 + 64 + 2 * n] = loR; H[p * 136 + 64 + 2 * n + 1] = loI;
        float t1 = fmaf(wr, hR, fmaf(-wi, hI, sr));
        hI = fmaf(wr, hI, fmaf(wi, hR, si));
        hR = t1;
      }
    }
  }
  __syncthreads();

  // ---- phase 4: s = Y*Lt^T + Hin*Vt^T (hi+lo), + D*y, GELU ----
  // wave w8 owns j-tile w8*16 .. +15, all 8 row-tiles.
  const bf16* LtC = Lt + (size_t)c * 16384;
  const bf16* VtC = Vt + (size_t)c * 8192;
  floatx4 acc[8];
#pragma unroll
  for (int mi = 0; mi < 8; ++mi) acc[mi] = (floatx4){0.f, 0.f, 0.f, 0.f};
#pragma unroll
  for (int kk = 0; kk < 4; ++kk) {
    bf16x8 b0 = *(const bf16x8*)(LtC + (w8 * 16 + mh) * 128 + kk * 32 + quad * 8);
#pragma unroll
    for (int mi = 0; mi < 8; ++mi) {
      bf16x8 af = *(bf16x8*)&Y[(mi * 16 + mh) * 136 + kk * 32 + quad * 8];
      acc[mi] = __builtin_amdgcn_mfma_f32_16x16x32_bf16(af, b0, acc[mi], 0, 0, 0);
    }
  }
#pragma unroll
  for (int kk = 0; kk < 2; ++kk) {
    bf16x8 v0 = *(const bf16x8*)(VtC + (w8 * 16 + mh) * 64 + kk * 32 + quad * 8);
#pragma unroll
    for (int mi = 0; mi < 8; ++mi) {
      bf16x8 ah = *(bf16x8*)&H[(mi * 16 + mh) * 136 + kk * 32 + quad * 8];
      bf16x8 al = *(bf16x8*)&H[(mi * 16 + mh) * 136 + 64 + kk * 32 + quad * 8];
      acc[mi] = __builtin_amdgcn_mfma_f32_16x16x32_bf16(ah, v0, acc[mi], 0, 0, 0);
      acc[mi] = __builtin_amdgcn_mfma_f32_16x16x32_bf16(al, v0, acc[mi], 0, 0, 0);
    }
  }
  // epilogue: u = GELU(s + D*y) — tanh-form GELU via exp2/rcp (max |err| ~3e-4)
  bf16 ub[8][4];
  int jcol = w8 * 16 + mh;
#pragma unroll
  for (int mi = 0; mi < 8; ++mi)
#pragma unroll
    for (int r = 0; r < 4; ++r) {
      int p = mi * 16 + quad * 4 + r;
      float y = (float)Y[p * 136 + jcol];
      float sv = fmaf(Dc, y, acc[mi][r]);
      float s3 = sv * sv * sv;
      float zz = 0.7978845608028654f * fmaf(0.044715f, s3, sv);
      float e = __builtin_amdgcn_exp2f(zz * 2.8853900817779268f);  // exp(2z)
      float th = 1.f - 2.f * __builtin_amdgcn_rcpf(e + 1.f);
      ub[mi][r] = (bf16)(0.5f * sv * (1.f + th));
    }
  __syncthreads();   // all Y/H reads complete
#pragma unroll
  for (int mi = 0; mi < 8; ++mi)
#pragma unroll
    for (int r = 0; r < 4; ++r) {
      int p = mi * 16 + quad * 4 + r;
      Y[p * 136 + jcol] = ub[mi][r];
    }
  __syncthreads();
  // coalesced writeout U[b][c][t]
  bf16* Uc = U + (size_t)(b * cC + c) * cT;
#pragma unroll
  for (int it = 0; it < 8; ++it) {
    int i4 = tid + it * 512;
    if (i4 < 4000) {
      int t = i4 * 4, p = t >> 7, j = t & 127;
      *(bf16x4*)(Uc + t) = *(bf16x4*)&Y[p * 136 + j];
    }
  }
}

// ---------------- gemm2: z = W_out @ u (+bias, GLU, +residual), U in [b][c][t] ----------------
// Persistent pipelined: 500 blocks x 512 thr, 4 token-tiles per block,
// double-buffered LDS; next tile's U loads issued before MFMA, ds_write after
// epilogue, ONE barrier per iteration. Hides stage latency under MFMA+epilogue.
__global__ __launch_bounds__(512, 4)
void gemm2_kernel(const bf16* __restrict__ U, const bf16* __restrict__ Wb,
                  const float* __restrict__ b_out, const float* __restrict__ x,
                  float* __restrict__ out) {
  __shared__ __align__(16) bf16 Ut[2][64 * 264];
  constexpr int NBLK = 500;
  int tid = threadIdx.x, lane = tid & 63, w = tid >> 6, quad = lane >> 4, mh = lane & 15;
  int cs = tid & 255, th = tid >> 8;     // staging role: channel, t-half

  bf16x8 pre[4];
  // prologue: load tile0 -> regs -> Ut[0]
  {
    int tile = blockIdx.x;
    int tb = tile % 250, b = tile / 250;
    const bf16* src = U + (size_t)(b * cC + cs) * cT + tb * 64 + th * 32;
#pragma unroll
    for (int g = 0; g < 4; ++g) pre[g] = *(const bf16x8*)(src + g * 8);
#pragma unroll
    for (int g = 0; g < 4; ++g) {
      bf16x8 v = pre[g];
#pragma unroll
      for (int k = 0; k < 8; ++k) Ut[0][(th * 32 + g * 8 + k) * 264 + cs] = v[k];
    }
  }
  __syncthreads();

#pragma unroll 1
  for (int i = 0; i < 4; ++i) {
    int buf = i & 1;
    int tile = blockIdx.x + i * NBLK;
    int tb = tile % 250, b = tile / 250;
    int t0 = tb * 64;
    // issue next tile's loads (latency hidden under MFMA + epilogue)
    if (i < 3) {
      int ntile = tile + NBLK;
      int ntb = ntile % 250, nb = ntile / 250;
      const bf16* src = U + (size_t)(nb * cC + cs) * cT + ntb * 64 + th * 32;
#pragma unroll
      for (int g = 0; g < 4; ++g) pre[g] = *(const bf16x8*)(src + g * 8);
    }
    // ---- MFMA from Ut[buf] ----
    floatx4 a1[2][4], a2[2][4];
#pragma unroll
    for (int oj = 0; oj < 2; ++oj)
#pragma unroll
      for (int tt = 0; tt < 4; ++tt) {
        a1[oj][tt] = (floatx4){0.f, 0.f, 0.f, 0.f};
        a2[oj][tt] = (floatx4){0.f, 0.f, 0.f, 0.f};
      }
#pragma unroll
    for (int kk = 0; kk < 8; ++kk) {
      int ko = kk * 32 + quad * 8;
      bf16x8 wf1[2], wf2[2];
#pragma unroll
      for (int oj = 0; oj < 2; ++oj) {
        int o = w * 32 + oj * 16 + mh;
        wf1[oj] = *(const bf16x8*)(Wb + (size_t)o * 256 + ko);
        wf2[oj] = *(const bf16x8*)(Wb + (size_t)(o + 256) * 256 + ko);
      }
#pragma unroll
      for (int tt = 0; tt < 4; ++tt) {
        bf16x8 uf = *(bf16x8*)&Ut[buf][(tt * 16 + mh) * 264 + ko];
#pragma unroll
        for (int oj = 0; oj < 2; ++oj) {
          a1[oj][tt] = __builtin_amdgcn_mfma_f32_16x16x32_bf16(wf1[oj], uf, a1[oj][tt], 0, 0, 0);
          a2[oj][tt] = __builtin_amdgcn_mfma_f32_16x16x32_bf16(wf2[oj], uf, a2[oj][tt], 0, 0, 0);
        }
      }
    }
    // ---- epilogue: bias, GLU, residual ----
#pragma unroll
    for (int oj = 0; oj < 2; ++oj)
#pragma unroll
      for (int tt = 0; tt < 4; ++tt)
#pragma unroll
        for (int r = 0; r < 4; ++r) {
          int o = w * 32 + oj * 16 + quad * 4 + r;
          int t = t0 + tt * 16 + mh;
          float z1 = a1[oj][tt][r] + b_out[o];
          float z2 = a2[oj][tt][r] + b_out[o + 256];
          float sg = fast_sigmoid(z2);
          size_t idx = (size_t)(b * cC + o) * cT + t;
          out[idx] = x[idx] + z1 * sg;
        }
    // ---- write next tile into the other buffer ----
    if (i < 3) {
#pragma unroll
      for (int g = 0; g < 4; ++g) {
        bf16x8 v = pre[g];
#pragma unroll
        for (int k = 0; k < 8; ++k) Ut[buf ^ 1][(th * 32 + g * 8 + k) * 264 + cs] = v[k];
      }
      __syncthreads();   // writes visible; also all waves done reading Ut[buf]
    }
  }
}

extern "C" void kernel_launch(void* const* d_in, const int* in_sizes, int n_in,
                              void* d_out, int out_size, void* d_ws, size_t ws_size,
                              hipStream_t stream) {
  const float* x          = (const float*)d_in[0];
  const float* gamma      = (const float*)d_in[1];
  const float* beta       = (const float*)d_in[2];
  const float* prelu_w    = (const float*)d_in[3];
  const float* log_dt     = (const float*)d_in[4];
  const float* log_A_real = (const float*)d_in[5];
  const float* A_imag     = (const float*)d_in[6];
  const float* C_re       = (const float*)d_in[7];
  const float* C_im       = (const float*)d_in[8];
  const float* Dp         = (const float*)d_in[9];
  const float* W_out      = (const float*)d_in[10];
  const float* b_out      = (const float*)d_in[11];
  float* out = (float*)d_out;
  char* ws = (char*)d_ws;

  float* meanp = (float*)(ws + kMean);
  float* rstdp = (float*)(ws + kRstd);
  float* wlr   = (float*)(ws + kWlr);
  float* wli   = (float*)(ws + kWli);
  bf16*  Wb    = (bf16*)(ws + kWb);
  bf16*  Lt    = (bf16*)(ws + kLt);
  bf16*  Et    = (bf16*)(ws + kEt);
  bf16*  Vt    = (bf16*)(ws + kVt);
  bf16*  U     = (bf16*)(ws + kU);

  prepW_kernel<<<512, 256, 0, stream>>>(W_out, Wb);
  prep2_kernel<<<256, 128, 0, stream>>>(log_dt, log_A_real, A_imag, C_re, C_im,
                                        wlr, wli, Lt, Et, Vt);
  stats_kernel<<<(cB * cT) / 128, 512, 0, stream>>>(x, meanp, rstdp);
  scanM_kernel<<<cB * cC, 512, 0, stream>>>(x, meanp, rstdp, gamma, beta, prelu_w,
                                            Dp, wlr, wli, Lt, Et, Vt, U);
  gemm2_kernel<<<500, 512, 0, stream>>>(U, Wb, b_out, x, out);
}

// Round 7
// 445.500 us; speedup vs baseline: 1.3189x; 1.3189x over previous
//
#include <hip/hip_runtime.h>
#include <cstdint>
#include <cstddef>

// Problem constants
constexpr int cB = 8, cC = 256, cT = 16000, cN = 32;
constexpr int cP = 125;            // chunks per sequence (125*128 = 16000)
constexpr float cEPS = 1e-8f;

typedef __bf16 bf16;
typedef __bf16 bf16x4 __attribute__((ext_vector_type(4)));
typedef __bf16 bf16x8 __attribute__((ext_vector_type(8)));
typedef float floatx4 __attribute__((ext_vector_type(4)));

// Workspace layout (bytes), all 16B-aligned
constexpr size_t kMean = 0;                                // B*T f32
constexpr size_t kRstd = kMean + (size_t)cB * cT * 4;      // B*T f32
constexpr size_t kWlr  = kRstd + (size_t)cB * cT * 4;      // C*32 f32 (w^128 re)
constexpr size_t kWli  = kWlr + (size_t)cC * cN * 4;       // C*32 f32 (w^128 im)
constexpr size_t kWb   = kWli + (size_t)cC * cN * 4;       // 512*256 bf16
constexpr size_t kLt   = kWb  + (size_t)512 * 256 * 2;     // C*128*128 bf16 (Toeplitz, row j: k[j-i])
constexpr size_t kEt   = kLt  + (size_t)cC * 128 * 128 * 2;// C*64*128 bf16 (state extraction)
constexpr size_t kVt   = kEt  + (size_t)cC * 64 * 128 * 2; // C*128*64 bf16 (correction)
constexpr size_t kU    = kVt  + (size_t)cC * 128 * 64 * 2; // B*C*T bf16 (u, [b][c][t])

__device__ __forceinline__ float fast_sigmoid(float z) {
  return __builtin_amdgcn_rcpf(1.f + __builtin_amdgcn_exp2f(-z * 1.4426950408889634f));
}

// ---------------- fused prep: stats (blocks 0..999) + prep2/prepW (blocks 1000..1255) ----------------
// These three jobs are mutually independent; fusing them removes two graph nodes
// (per-node launch overhead ~30 us each, the invisible ~150 us in rounds 2-5).
__global__ __launch_bounds__(512)
void prep_stats_kernel(const float* __restrict__ x,
                       const float* __restrict__ log_dt,
                       const float* __restrict__ log_A_real,
                       const float* __restrict__ A_imag,
                       const float* __restrict__ C_re,
                       const float* __restrict__ C_im,
                       const float* __restrict__ W_out,
                       float* __restrict__ meanp, float* __restrict__ rstdp,
                       float* __restrict__ wlr, float* __restrict__ wli,
                       bf16* __restrict__ Wb, bf16* __restrict__ Lt,
                       bf16* __restrict__ Et, bf16* __restrict__ Vt) {
  int blk = blockIdx.x;
  if (blk < 1000) {
    // ---- stats path: 128 tokens per block, 8 c-groups of 32, float2 loads ----
    __shared__ float S1[8][128], S2[8][128];
    int g0 = blk * 128;
    int b = g0 / cT;
    int t0 = g0 - b * cT;
    int tp = threadIdx.x & 63, cq = threadIdx.x >> 6;
    const float2* xp = (const float2*)(x + ((size_t)b * cC + cq * 32) * cT + t0) + tp;
    float s1x = 0.f, s1y = 0.f, s2x = 0.f, s2y = 0.f;
#pragma unroll 8
    for (int cc = 0; cc < 32; ++cc) {
      float2 v = xp[(size_t)cc * (cT / 2)];
      s1x += v.x; s2x = fmaf(v.x, v.x, s2x);
      s1y += v.y; s2y = fmaf(v.y, v.y, s2y);
    }
    S1[cq][2 * tp] = s1x; S1[cq][2 * tp + 1] = s1y;
    S2[cq][2 * tp] = s2x; S2[cq][2 * tp + 1] = s2y;
    __syncthreads();
    if (threadIdx.x < 128) {
      float a1 = 0.f, a2 = 0.f;
#pragma unroll
      for (int q = 0; q < 8; ++q) { a1 += S1[q][threadIdx.x]; a2 += S2[q][threadIdx.x]; }
      float mean = a1 * (1.0f / cC);
      float var = fmaf(a2, 1.0f / cC, -mean * mean);
      int g = g0 + threadIdx.x;
      meanp[g] = mean;
      rstdp[g] = rsqrtf(var + cEPS);
    }
  } else {
    // ---- prep2 + prepW path: one channel per block ----
    __shared__ float kv[128];
    int c = blk - 1000;          // 0..255
    int tid = threadIdx.x;
    // prepW slice: 256 blocks x 512 threads = 131072 = 512*256 elements
    {
      int idx = c * 512 + tid;
      Wb[idx] = (bf16)W_out[idx];
    }
    if (tid < 128) {
      int j = tid;
      float dt = expf(log_dt[c]);
      float kj = 0.f;
      for (int n = 0; n < cN; ++n) {
        int idx = c * cN + n;
        float Ar = -expf(log_A_real[idx]);
        float Ai = A_imag[idx];
        float ar = dt * Ar, ai = dt * Ai;           // dtA
        float mg = expf(ar), cw, sw;
        sincosf(ai, &sw, &cw);
        float wre = mg * cw, wim = mg * sw;
        float den = Ar * Ar + Ai * Ai;
        float emr = wre - 1.f, emi = wim;
        float qr = (emr * Ar + emi * Ai) / den;
        float qi = (emi * Ar - emr * Ai) / den;
        float cre = C_re[idx], cim = C_im[idx];
        float c2r = 2.f * (cre * qr - cim * qi);
        float c2i = 2.f * (cre * qi + cim * qr);
        float mj = expf((float)j * ar), cj, sj;
        sincosf((float)j * ai, &sj, &cj);
        float wjr = mj * cj, wji = mj * sj;
        kj += c2r * wjr - c2i * wji;                 // k[j] = Re(Cc2 * w^j)
        float w1r = wjr * wre - wji * wim;
        float w1i = wjr * wim + wji * wre;
        Vt[(size_t)c * 8192 + j * 64 + 2 * n]     = (bf16)(c2r * w1r - c2i * w1i);
        Vt[(size_t)c * 8192 + j * 64 + 2 * n + 1] = (bf16)(-(c2r * w1i + c2i * w1r));
        float mr = expf((float)(127 - j) * ar), cr2, sr2;
        sincosf((float)(127 - j) * ai, &sr2, &cr2);
        Et[(size_t)c * 8192 + (2 * n) * 128 + j]     = (bf16)(mr * cr2);
        Et[(size_t)c * 8192 + (2 * n + 1) * 128 + j] = (bf16)(mr * sr2);
      }
      kv[j] = kj;
      if (j < cN) {      // w^128 for the chunk prefix
        int idx = c * cN + j;
        float Ar = -expf(log_A_real[idx]);
        float ai = dt * A_imag[idx], ar = dt * Ar;
        float m = expf(128.f * ar), cc, ss;
        sincosf(128.f * ai, &ss, &cc);
        wlr[idx] = m * cc;
        wli[idx] = m * ss;
      }
    }
    __syncthreads();
    // Lt[row][col] = k[row-col] for col<=row else 0 — coalesced, all 512 threads
    bf16* LtC = Lt + (size_t)c * 16384;
    for (int e = tid; e < 4096; e += 512) {
      int t4 = e * 4;
      int row = t4 >> 7, col = t4 & 127;
      bf16x4 v;
#pragma unroll
      for (int q = 0; q < 4; ++q) {
        int ii = col + q;
        v[q] = (ii <= row) ? (bf16)kv[row - ii] : (bf16)0.f;
      }
      *(bf16x4*)(LtC + row * 128 + col) = v;
    }
  }
}

// ---------------- scanM: LN+PReLU -> MFMA chunked scan -> skip -> GELU -> U[b][c][t] ----------------
// 512 threads (8 waves), 2 blocks/CU -> 16 waves/CU. XCD-swizzled so the 8 b-siblings
// of one channel land on the same XCD (share Lt/Et/Vt in that XCD's L2).
__global__ __launch_bounds__(512, 4)
void scanM_kernel(const float* __restrict__ x, const float* __restrict__ meanp,
                  const float* __restrict__ rstdp, const float* __restrict__ gam,
                  const float* __restrict__ bet, const float* __restrict__ prw,
                  const float* __restrict__ Dp,
                  const float* __restrict__ wlr, const float* __restrict__ wli,
                  const bf16* __restrict__ Lt, const bf16* __restrict__ Et,
                  const bf16* __restrict__ Vt, bf16* __restrict__ U) {
  __shared__ __align__(16) bf16 Y[128 * 136];
  __shared__ __align__(16) bf16 H[128 * 136];
  __shared__ float Sseg[8][32][2];

  int blk = blockIdx.x;
  // XCD chunk swizzle (2048 % 8 == 0, bijective)
  int logical = (blk & 7) * 256 + (blk >> 3);
  int b = logical & 7, c = logical >> 3;
  int tid = threadIdx.x;
  int lane = tid & 63, w8 = tid >> 6, quad = lane >> 4, mh = lane & 15;
  float gamma = gam[c], beta = bet[c], pw = prw[c], Dc = Dp[c];

  // ---- phase 1: y = PReLU(LN(x)) -> Y LDS (bf16) ----
  const float4* x4 = (const float4*)(x + (size_t)(b * cC + c) * cT);
  const float4* m4 = (const float4*)(meanp + (size_t)b * cT);
  const float4* r4 = (const float4*)(rstdp + (size_t)b * cT);
#pragma unroll
  for (int it = 0; it < 8; ++it) {
    int i4 = tid + it * 512;
    if (i4 < 4000) {
      float4 xv = x4[i4], mv = m4[i4], rv = r4[i4];
      int t = i4 * 4, p = t >> 7, j = t & 127;
      float ys[4];
      ys[0] = fmaf((xv.x - mv.x) * rv.x, gamma, beta);
      ys[1] = fmaf((xv.y - mv.y) * rv.y, gamma, beta);
      ys[2] = fmaf((xv.z - mv.z) * rv.z, gamma, beta);
      ys[3] = fmaf((xv.w - mv.w) * rv.w, gamma, beta);
      bf16x4 yv;
#pragma unroll
      for (int q = 0; q < 4; ++q) {
        float y = ys[q];
        yv[q] = (bf16)(y >= 0.f ? y : y * pw);
      }
      *(bf16x4*)&Y[p * 136 + j] = yv;
    }
  }
  for (int e = tid; e < 3 * 136; e += 512) Y[125 * 136 + e] = (bf16)0.f;  // pad rows
  __syncthreads();

  // ---- phase 2: extraction H[p][comp] = sum_i Y[p][i]*Et[comp][i]; store bf16 hi/lo ----
  const bf16* EtC = Et + (size_t)c * 8192;
  int cgrp = (w8 & 3) * 16, mbase = (w8 >> 2) * 4;
  floatx4 hacc[4];
#pragma unroll
  for (int mi = 0; mi < 4; ++mi) hacc[mi] = (floatx4){0.f, 0.f, 0.f, 0.f};
#pragma unroll
  for (int kk = 0; kk < 4; ++kk) {
    bf16x8 bfrag = *(const bf16x8*)(EtC + (cgrp + mh) * 128 + kk * 32 + quad * 8);
#pragma unroll
    for (int mi = 0; mi < 4; ++mi) {
      bf16x8 af = *(bf16x8*)&Y[((mbase + mi) * 16 + mh) * 136 + kk * 32 + quad * 8];
      hacc[mi] = __builtin_amdgcn_mfma_f32_16x16x32_bf16(af, bfrag, hacc[mi], 0, 0, 0);
    }
  }
#pragma unroll
  for (int mi = 0; mi < 4; ++mi) {
#pragma unroll
    for (int r = 0; r < 4; ++r) {
      int p = (mbase + mi) * 16 + quad * 4 + r;
      int comp = cgrp + mh;
      float v = hacc[mi][r];
      bf16 hi = (bf16)v;
      bf16 lo = (bf16)(v - (float)hi);
      H[p * 136 + comp] = hi;
      H[p * 136 + 64 + comp] = lo;
    }
  }
  __syncthreads();

  // ---- phase 3: segmented prefix over chunks (exclusive), in place (first 256 thr) ----
  {
    int n = tid & 31, sg = (tid >> 5) & 7;
    int p0 = sg * 16;
    int p1 = (p0 + 16 < cP) ? p0 + 16 : cP;
    float wr = wlr[c * cN + n], wi = wli[c * cN + n];
    float hR = 0.f, hI = 0.f;
    if (tid < 256) {
      for (int p = p0; p < p1; ++p) {
        float sr = (float)H[p * 136 + 2 * n] + (float)H[p * 136 + 64 + 2 * n];
        float si = (float)H[p * 136 + 2 * n + 1] + (float)H[p * 136 + 64 + 2 * n + 1];
        float t1 = fmaf(wr, hR, fmaf(-wi, hI, sr));
        hI = fmaf(wr, hI, fmaf(wi, hR, si));
        hR = t1;
      }
      Sseg[sg][n][0] = hR; Sseg[sg][n][1] = hI;
    }
    __syncthreads();
    if (tid < 32) {
      float ar = wr, ai = wi;       // (w^128)^16 via 4 squarings
      for (int q = 0; q < 4; ++q) {
        float nr = ar * ar - ai * ai;
        ai = 2.f * ar * ai; ar = nr;
      }
      float HR = 0.f, HI = 0.f;
      for (int s2 = 0; s2 < 8; ++s2) {
        float fr = Sseg[s2][n][0], fi = Sseg[s2][n][1];
        Sseg[s2][n][0] = HR; Sseg[s2][n][1] = HI;
        float t1 = fmaf(ar, HR, fmaf(-ai, HI, fr));
        HI = fmaf(ar, HI, fmaf(ai, HR, fi));
        HR = t1;
      }
    }
    __syncthreads();
    if (tid < 256) {
      hR = Sseg[sg][n][0]; hI = Sseg[sg][n][1];
      for (int p = p0; p < p1; ++p) {
        float sr = (float)H[p * 136 + 2 * n] + (float)H[p * 136 + 64 + 2 * n];
        float si = (float)H[p * 136 + 2 * n + 1] + (float)H[p * 136 + 64 + 2 * n + 1];
        bf16 hiR = (bf16)hR; bf16 loR = (bf16)(hR - (float)hiR);
        bf16 hiI = (bf16)hI; bf16 loI = (bf16)(hI - (float)hiI);
        H[p * 136 + 2 * n] = hiR;      H[p * 136 + 2 * n + 1] = hiI;
        H[p * 136 + 64 + 2 * n] = loR; H[p * 136 + 64 + 2 * n + 1] = loI;
        float t1 = fmaf(wr, hR, fmaf(-wi, hI, sr));
        hI = fmaf(wr, hI, fmaf(wi, hR, si));
        hR = t1;
      }
    }
  }
  __syncthreads();

  // ---- phase 4: s = Y*Lt^T + Hin*Vt^T (hi+lo), + D*y, GELU ----
  const bf16* LtC = Lt + (size_t)c * 16384;
  const bf16* VtC = Vt + (size_t)c * 8192;
  floatx4 acc[8];
#pragma unroll
  for (int mi = 0; mi < 8; ++mi) acc[mi] = (floatx4){0.f, 0.f, 0.f, 0.f};
#pragma unroll
  for (int kk = 0; kk < 4; ++kk) {
    bf16x8 b0 = *(const bf16x8*)(LtC + (w8 * 16 + mh) * 128 + kk * 32 + quad * 8);
#pragma unroll
    for (int mi = 0; mi < 8; ++mi) {
      bf16x8 af = *(bf16x8*)&Y[(mi * 16 + mh) * 136 + kk * 32 + quad * 8];
      acc[mi] = __builtin_amdgcn_mfma_f32_16x16x32_bf16(af, b0, acc[mi], 0, 0, 0);
    }
  }
#pragma unroll
  for (int kk = 0; kk < 2; ++kk) {
    bf16x8 v0 = *(const bf16x8*)(VtC + (w8 * 16 + mh) * 64 + kk * 32 + quad * 8);
#pragma unroll
    for (int mi = 0; mi < 8; ++mi) {
      bf16x8 ah = *(bf16x8*)&H[(mi * 16 + mh) * 136 + kk * 32 + quad * 8];
      bf16x8 al = *(bf16x8*)&H[(mi * 16 + mh) * 136 + 64 + kk * 32 + quad * 8];
      acc[mi] = __builtin_amdgcn_mfma_f32_16x16x32_bf16(ah, v0, acc[mi], 0, 0, 0);
      acc[mi] = __builtin_amdgcn_mfma_f32_16x16x32_bf16(al, v0, acc[mi], 0, 0, 0);
    }
  }
  // epilogue: u = GELU(s + D*y) — tanh-form GELU via exp2/rcp (max |err| ~3e-4)
  bf16 ub[8][4];
  int jcol = w8 * 16 + mh;
#pragma unroll
  for (int mi = 0; mi < 8; ++mi)
#pragma unroll
    for (int r = 0; r < 4; ++r) {
      int p = mi * 16 + quad * 4 + r;
      float y = (float)Y[p * 136 + jcol];
      float sv = fmaf(Dc, y, acc[mi][r]);
      float s3 = sv * sv * sv;
      float zz = 0.7978845608028654f * fmaf(0.044715f, s3, sv);
      float e = __builtin_amdgcn_exp2f(zz * 2.8853900817779268f);  // exp(2z)
      float th = 1.f - 2.f * __builtin_amdgcn_rcpf(e + 1.f);
      ub[mi][r] = (bf16)(0.5f * sv * (1.f + th));
    }
  __syncthreads();   // all Y/H reads complete
#pragma unroll
  for (int mi = 0; mi < 8; ++mi)
#pragma unroll
    for (int r = 0; r < 4; ++r) {
      int p = mi * 16 + quad * 4 + r;
      Y[p * 136 + jcol] = ub[mi][r];
    }
  __syncthreads();
  // coalesced writeout U[b][c][t]
  bf16* Uc = U + (size_t)(b * cC + c) * cT;
#pragma unroll
  for (int it = 0; it < 8; ++it) {
    int i4 = tid + it * 512;
    if (i4 < 4000) {
      int t = i4 * 4, p = t >> 7, j = t & 127;
      *(bf16x4*)(Uc + t) = *(bf16x4*)&Y[p * 136 + j];
    }
  }
}

// ---------------- gemm2: z = W_out @ u (+bias, GLU, +residual), U in [b][c][t] ----------------
// Round-5 version (known good, 133.5 us): 512 threads (8 waves), 64 tokens x ALL 512
// out-channels, U-tile read once. 124 regs total (60 V + 64 A) -> no spill at (512,4).
__global__ __launch_bounds__(512, 4)
void gemm2_kernel(const bf16* __restrict__ U, const bf16* __restrict__ Wb,
                  const float* __restrict__ b_out, const float* __restrict__ x,
                  float* __restrict__ out) {
  __shared__ __align__(16) bf16 Ut[64 * 264];
  int bx = blockIdx.x;        // 0..1999
  int tb = bx % 250, b = bx / 250;
  int t0 = tb * 64;
  int tid = threadIdx.x, lane = tid & 63, w = tid >> 6, quad = lane >> 4, mh = lane & 15;
  // stage: 512 threads: c = tid&255, th = tid>>8, each stages 32 t values into Ut[t][c]
  {
    int c = tid & 255, th = tid >> 8;
    const bf16* src = U + (size_t)(b * cC + c) * cT + t0 + th * 32;
#pragma unroll
    for (int g = 0; g < 4; ++g) {
      bf16x8 v = *(const bf16x8*)(src + g * 8);
#pragma unroll
      for (int k = 0; k < 8; ++k) Ut[(th * 32 + g * 8 + k) * 264 + c] = v[k];
    }
  }
  __syncthreads();
  floatx4 a1[2][4], a2[2][4];
#pragma unroll
  for (int oj = 0; oj < 2; ++oj)
#pragma unroll
    for (int tt = 0; tt < 4; ++tt) {
      a1[oj][tt] = (floatx4){0.f, 0.f, 0.f, 0.f};
      a2[oj][tt] = (floatx4){0.f, 0.f, 0.f, 0.f};
    }
#pragma unroll
  for (int kk = 0; kk < 8; ++kk) {
    int ko = kk * 32 + quad * 8;
    bf16x8 wf1[2], wf2[2];
#pragma unroll
    for (int oj = 0; oj < 2; ++oj) {
      int o = w * 32 + oj * 16 + mh;
      wf1[oj] = *(const bf16x8*)(Wb + (size_t)o * 256 + ko);
      wf2[oj] = *(const bf16x8*)(Wb + (size_t)(o + 256) * 256 + ko);
    }
#pragma unroll
    for (int tt = 0; tt < 4; ++tt) {
      bf16x8 uf = *(bf16x8*)&Ut[(tt * 16 + mh) * 264 + ko];
#pragma unroll
      for (int oj = 0; oj < 2; ++oj) {
        a1[oj][tt] = __builtin_amdgcn_mfma_f32_16x16x32_bf16(wf1[oj], uf, a1[oj][tt], 0, 0, 0);
        a2[oj][tt] = __builtin_amdgcn_mfma_f32_16x16x32_bf16(wf2[oj], uf, a2[oj][tt], 0, 0, 0);
      }
    }
  }
#pragma unroll
  for (int oj = 0; oj < 2; ++oj)
#pragma unroll
    for (int tt = 0; tt < 4; ++tt)
#pragma unroll
      for (int r = 0; r < 4; ++r) {
        int o = w * 32 + oj * 16 + quad * 4 + r;
        int t = t0 + tt * 16 + mh;
        float z1 = a1[oj][tt][r] + b_out[o];
        float z2 = a2[oj][tt][r] + b_out[o + 256];
        float sg = fast_sigmoid(z2);
        size_t idx = (size_t)(b * cC + o) * cT + t;
        out[idx] = x[idx] + z1 * sg;
      }
}

extern "C" void kernel_launch(void* const* d_in, const int* in_sizes, int n_in,
                              void* d_out, int out_size, void* d_ws, size_t ws_size,
                              hipStream_t stream) {
  const float* x          = (const float*)d_in[0];
  const float* gamma      = (const float*)d_in[1];
  const float* beta       = (const float*)d_in[2];
  const float* prelu_w    = (const float*)d_in[3];
  const float* log_dt     = (const float*)d_in[4];
  const float* log_A_real = (const float*)d_in[5];
  const float* A_imag     = (const float*)d_in[6];
  const float* C_re       = (const float*)d_in[7];
  const float* C_im       = (const float*)d_in[8];
  const float* Dp         = (const float*)d_in[9];
  const float* W_out      = (const float*)d_in[10];
  const float* b_out      = (const float*)d_in[11];
  float* out = (float*)d_out;
  char* ws = (char*)d_ws;

  float* meanp = (float*)(ws + kMean);
  float* rstdp = (float*)(ws + kRstd);
  float* wlr   = (float*)(ws + kWlr);
  float* wli   = (float*)(ws + kWli);
  bf16*  Wb    = (bf16*)(ws + kWb);
  bf16*  Lt    = (bf16*)(ws + kLt);
  bf16*  Et    = (bf16*)(ws + kEt);
  bf16*  Vt    = (bf16*)(ws + kVt);
  bf16*  U     = (bf16*)(ws + kU);

  prep_stats_kernel<<<1256, 512, 0, stream>>>(x, log_dt, log_A_real, A_imag, C_re,
                                              C_im, W_out, meanp, rstdp, wlr, wli,
                                              Wb, Lt, Et, Vt);
  scanM_kernel<<<cB * cC, 512, 0, stream>>>(x, meanp, rstdp, gamma, beta, prelu_w,
                                            Dp, wlr, wli, Lt, Et, Vt, U);
  gemm2_kernel<<<cB * (cT / 64), 512, 0, stream>>>(U, Wb, b_out, x, out);
}

// Round 8
// 431.193 us; speedup vs baseline: 1.3626x; 1.0332x over previous
//
#include <hip/hip_runtime.h>
#include <cstdint>
#include <cstddef>

// Problem constants
constexpr int cB = 8, cC = 256, cT = 16000, cN = 32;
constexpr int cP = 125;            // chunks per sequence (125*128 = 16000)
constexpr float cEPS = 1e-8f;

typedef __bf16 bf16;
typedef __bf16 bf16x4 __attribute__((ext_vector_type(4)));
typedef __bf16 bf16x8 __attribute__((ext_vector_type(8)));
typedef float floatx4 __attribute__((ext_vector_type(4)));

// Workspace layout (bytes), all 16B-aligned
constexpr size_t kMean = 0;                                // B*T f32
constexpr size_t kRstd = kMean + (size_t)cB * cT * 4;      // B*T f32
constexpr size_t kWlr  = kRstd + (size_t)cB * cT * 4;      // C*32 f32 (w^128 re)
constexpr size_t kWli  = kWlr + (size_t)cC * cN * 4;       // C*32 f32 (w^128 im)
constexpr size_t kWb   = kWli + (size_t)cC * cN * 4;       // 512*256 bf16
constexpr size_t kLt   = kWb  + (size_t)512 * 256 * 2;     // C*128*128 bf16 (Toeplitz, row j: k[j-i])
constexpr size_t kEt   = kLt  + (size_t)cC * 128 * 128 * 2;// C*64*128 bf16 (state extraction)
constexpr size_t kVt   = kEt  + (size_t)cC * 64 * 128 * 2; // C*128*64 bf16 (correction)
constexpr size_t kU    = kVt  + (size_t)cC * 128 * 64 * 2; // B*C*T bf16 (u, [b][c][t])

__device__ __forceinline__ float fast_sigmoid(float z) {
  return __builtin_amdgcn_rcpf(1.f + __builtin_amdgcn_exp2f(-z * 1.4426950408889634f));
}

// ---------------- fused prep: stats (blocks 0..999) + prep2/prepW (blocks 1000..1255) ----------------
__global__ __launch_bounds__(512)
void prep_stats_kernel(const float* __restrict__ x,
                       const float* __restrict__ log_dt,
                       const float* __restrict__ log_A_real,
                       const float* __restrict__ A_imag,
                       const float* __restrict__ C_re,
                       const float* __restrict__ C_im,
                       const float* __restrict__ W_out,
                       float* __restrict__ meanp, float* __restrict__ rstdp,
                       float* __restrict__ wlr, float* __restrict__ wli,
                       bf16* __restrict__ Wb, bf16* __restrict__ Lt,
                       bf16* __restrict__ Et, bf16* __restrict__ Vt) {
  int blk = blockIdx.x;
  if (blk < 1000) {
    // ---- stats path: 128 tokens per block, 8 c-groups of 32, float2 loads ----
    __shared__ float S1[8][128], S2[8][128];
    int g0 = blk * 128;
    int b = g0 / cT;
    int t0 = g0 - b * cT;
    int tp = threadIdx.x & 63, cq = threadIdx.x >> 6;
    const float2* xp = (const float2*)(x + ((size_t)b * cC + cq * 32) * cT + t0) + tp;
    float s1x = 0.f, s1y = 0.f, s2x = 0.f, s2y = 0.f;
#pragma unroll 8
    for (int cc = 0; cc < 32; ++cc) {
      float2 v = xp[(size_t)cc * (cT / 2)];
      s1x += v.x; s2x = fmaf(v.x, v.x, s2x);
      s1y += v.y; s2y = fmaf(v.y, v.y, s2y);
    }
    S1[cq][2 * tp] = s1x; S1[cq][2 * tp + 1] = s1y;
    S2[cq][2 * tp] = s2x; S2[cq][2 * tp + 1] = s2y;
    __syncthreads();
    if (threadIdx.x < 128) {
      float a1 = 0.f, a2 = 0.f;
#pragma unroll
      for (int q = 0; q < 8; ++q) { a1 += S1[q][threadIdx.x]; a2 += S2[q][threadIdx.x]; }
      float mean = a1 * (1.0f / cC);
      float var = fmaf(a2, 1.0f / cC, -mean * mean);
      int g = g0 + threadIdx.x;
      meanp[g] = mean;
      rstdp[g] = rsqrtf(var + cEPS);
    }
  } else {
    // ---- prep2 + prepW path: one channel per block ----
    __shared__ float kv[128];
    int c = blk - 1000;          // 0..255
    int tid = threadIdx.x;
    {
      int idx = c * 512 + tid;
      Wb[idx] = (bf16)W_out[idx];
    }
    if (tid < 128) {
      int j = tid;
      float dt = expf(log_dt[c]);
      float kj = 0.f;
      for (int n = 0; n < cN; ++n) {
        int idx = c * cN + n;
        float Ar = -expf(log_A_real[idx]);
        float Ai = A_imag[idx];
        float ar = dt * Ar, ai = dt * Ai;           // dtA
        float mg = expf(ar), cw, sw;
        sincosf(ai, &sw, &cw);
        float wre = mg * cw, wim = mg * sw;
        float den = Ar * Ar + Ai * Ai;
        float emr = wre - 1.f, emi = wim;
        float qr = (emr * Ar + emi * Ai) / den;
        float qi = (emi * Ar - emr * Ai) / den;
        float cre = C_re[idx], cim = C_im[idx];
        float c2r = 2.f * (cre * qr - cim * qi);
        float c2i = 2.f * (cre * qi + cim * qr);
        float mj = expf((float)j * ar), cj, sj;
        sincosf((float)j * ai, &sj, &cj);
        float wjr = mj * cj, wji = mj * sj;
        kj += c2r * wjr - c2i * wji;                 // k[j] = Re(Cc2 * w^j)
        float w1r = wjr * wre - wji * wim;
        float w1i = wjr * wim + wji * wre;
        Vt[(size_t)c * 8192 + j * 64 + 2 * n]     = (bf16)(c2r * w1r - c2i * w1i);
        Vt[(size_t)c * 8192 + j * 64 + 2 * n + 1] = (bf16)(-(c2r * w1i + c2i * w1r));
        float mr = expf((float)(127 - j) * ar), cr2, sr2;
        sincosf((float)(127 - j) * ai, &sr2, &cr2);
        Et[(size_t)c * 8192 + (2 * n) * 128 + j]     = (bf16)(mr * cr2);
        Et[(size_t)c * 8192 + (2 * n + 1) * 128 + j] = (bf16)(mr * sr2);
      }
      kv[j] = kj;
      if (j < cN) {      // w^128 for the chunk prefix
        int idx = c * cN + j;
        float Ar = -expf(log_A_real[idx]);
        float ai = dt * A_imag[idx], ar = dt * Ar;
        float m = expf(128.f * ar), cc, ss;
        sincosf(128.f * ai, &ss, &cc);
        wlr[idx] = m * cc;
        wli[idx] = m * ss;
      }
    }
    __syncthreads();
    // Lt[row][col] = k[row-col] for col<=row else 0 — coalesced, all 512 threads
    bf16* LtC = Lt + (size_t)c * 16384;
    for (int e = tid; e < 4096; e += 512) {
      int t4 = e * 4;
      int row = t4 >> 7, col = t4 & 127;
      bf16x4 v;
#pragma unroll
      for (int q = 0; q < 4; ++q) {
        int ii = col + q;
        v[q] = (ii <= row) ? (bf16)kv[row - ii] : (bf16)0.f;
      }
      *(bf16x4*)(LtC + row * 128 + col) = v;
    }
  }
}

// ---------------- scanM: LN+PReLU -> MFMA chunked scan -> skip -> GELU -> U[b][c][t] ----------------
// 512 threads (8 waves), 2 blocks/CU -> 16 waves/CU. XCD-swizzled.
__global__ __launch_bounds__(512, 4)
void scanM_kernel(const float* __restrict__ x, const float* __restrict__ meanp,
                  const float* __restrict__ rstdp, const float* __restrict__ gam,
                  const float* __restrict__ bet, const float* __restrict__ prw,
                  const float* __restrict__ Dp,
                  const float* __restrict__ wlr, const float* __restrict__ wli,
                  const bf16* __restrict__ Lt, const bf16* __restrict__ Et,
                  const bf16* __restrict__ Vt, bf16* __restrict__ U) {
  __shared__ __align__(16) bf16 Y[128 * 136];
  __shared__ __align__(16) bf16 H[128 * 136];
  __shared__ float Sseg[8][32][2];

  int blk = blockIdx.x;
  // XCD chunk swizzle (2048 % 8 == 0, bijective)
  int logical = (blk & 7) * 256 + (blk >> 3);
  int b = logical & 7, c = logical >> 3;
  int tid = threadIdx.x;
  int lane = tid & 63, w8 = tid >> 6, quad = lane >> 4, mh = lane & 15;
  float gamma = gam[c], beta = bet[c], pw = prw[c], Dc = Dp[c];

  // ---- phase 1: y = PReLU(LN(x)) -> Y LDS (bf16) ----
  const float4* x4 = (const float4*)(x + (size_t)(b * cC + c) * cT);
  const float4* m4 = (const float4*)(meanp + (size_t)b * cT);
  const float4* r4 = (const float4*)(rstdp + (size_t)b * cT);
#pragma unroll
  for (int it = 0; it < 8; ++it) {
    int i4 = tid + it * 512;
    if (i4 < 4000) {
      float4 xv = x4[i4], mv = m4[i4], rv = r4[i4];
      int t = i4 * 4, p = t >> 7, j = t & 127;
      float ys[4];
      ys[0] = fmaf((xv.x - mv.x) * rv.x, gamma, beta);
      ys[1] = fmaf((xv.y - mv.y) * rv.y, gamma, beta);
      ys[2] = fmaf((xv.z - mv.z) * rv.z, gamma, beta);
      ys[3] = fmaf((xv.w - mv.w) * rv.w, gamma, beta);
      bf16x4 yv;
#pragma unroll
      for (int q = 0; q < 4; ++q) {
        float y = ys[q];
        yv[q] = (bf16)(y >= 0.f ? y : y * pw);
      }
      *(bf16x4*)&Y[p * 136 + j] = yv;
    }
  }
  for (int e = tid; e < 3 * 136; e += 512) Y[125 * 136 + e] = (bf16)0.f;  // pad rows
  __syncthreads();

  // ---- phase 2: extraction H[p][comp] = sum_i Y[p][i]*Et[comp][i]; store bf16 hi/lo ----
  const bf16* EtC = Et + (size_t)c * 8192;
  int cgrp = (w8 & 3) * 16, mbase = (w8 >> 2) * 4;
  floatx4 hacc[4];
#pragma unroll
  for (int mi = 0; mi < 4; ++mi) hacc[mi] = (floatx4){0.f, 0.f, 0.f, 0.f};
#pragma unroll
  for (int kk = 0; kk < 4; ++kk) {
    bf16x8 bfrag = *(const bf16x8*)(EtC + (cgrp + mh) * 128 + kk * 32 + quad * 8);
#pragma unroll
    for (int mi = 0; mi < 4; ++mi) {
      bf16x8 af = *(bf16x8*)&Y[((mbase + mi) * 16 + mh) * 136 + kk * 32 + quad * 8];
      hacc[mi] = __builtin_amdgcn_mfma_f32_16x16x32_bf16(af, bfrag, hacc[mi], 0, 0, 0);
    }
  }
#pragma unroll
  for (int mi = 0; mi < 4; ++mi) {
#pragma unroll
    for (int r = 0; r < 4; ++r) {
      int p = (mbase + mi) * 16 + quad * 4 + r;
      int comp = cgrp + mh;
      float v = hacc[mi][r];
      bf16 hi = (bf16)v;
      bf16 lo = (bf16)(v - (float)hi);
      H[p * 136 + comp] = hi;
      H[p * 136 + 64 + comp] = lo;
    }
  }
  __syncthreads();

  // ---- phase 3: segmented prefix over chunks (exclusive), in place (first 256 thr) ----
  {
    int n = tid & 31, sg = (tid >> 5) & 7;
    int p0 = sg * 16;
    int p1 = (p0 + 16 < cP) ? p0 + 16 : cP;
    float wr = wlr[c * cN + n], wi = wli[c * cN + n];
    float hR = 0.f, hI = 0.f;
    if (tid < 256) {
      for (int p = p0; p < p1; ++p) {
        float sr = (float)H[p * 136 + 2 * n] + (float)H[p * 136 + 64 + 2 * n];
        float si = (float)H[p * 136 + 2 * n + 1] + (float)H[p * 136 + 64 + 2 * n + 1];
        float t1 = fmaf(wr, hR, fmaf(-wi, hI, sr));
        hI = fmaf(wr, hI, fmaf(wi, hR, si));
        hR = t1;
      }
      Sseg[sg][n][0] = hR; Sseg[sg][n][1] = hI;
    }
    __syncthreads();
    if (tid < 32) {
      float ar = wr, ai = wi;       // (w^128)^16 via 4 squarings
      for (int q = 0; q < 4; ++q) {
        float nr = ar * ar - ai * ai;
        ai = 2.f * ar * ai; ar = nr;
      }
      float HR = 0.f, HI = 0.f;
      for (int s2 = 0; s2 < 8; ++s2) {
        float fr = Sseg[s2][n][0], fi = Sseg[s2][n][1];
        Sseg[s2][n][0] = HR; Sseg[s2][n][1] = HI;
        float t1 = fmaf(ar, HR, fmaf(-ai, HI, fr));
        HI = fmaf(ar, HI, fmaf(ai, HR, fi));
        HR = t1;
      }
    }
    __syncthreads();
    if (tid < 256) {
      hR = Sseg[sg][n][0]; hI = Sseg[sg][n][1];
      for (int p = p0; p < p1; ++p) {
        float sr = (float)H[p * 136 + 2 * n] + (float)H[p * 136 + 64 + 2 * n];
        float si = (float)H[p * 136 + 2 * n + 1] + (float)H[p * 136 + 64 + 2 * n + 1];
        bf16 hiR = (bf16)hR; bf16 loR = (bf16)(hR - (float)hiR);
        bf16 hiI = (bf16)hI; bf16 loI = (bf16)(hI - (float)hiI);
        H[p * 136 + 2 * n] = hiR;      H[p * 136 + 2 * n + 1] = hiI;
        H[p * 136 + 64 + 2 * n] = loR; H[p * 136 + 64 + 2 * n + 1] = loI;
        float t1 = fmaf(wr, hR, fmaf(-wi, hI, sr));
        hI = fmaf(wr, hI, fmaf(wi, hR, si));
        hR = t1;
      }
    }
  }
  __syncthreads();

  // ---- phase 4: s = Y*Lt^T + Hin*Vt^T (hi+lo), + D*y, GELU ----
  const bf16* LtC = Lt + (size_t)c * 16384;
  const bf16* VtC = Vt + (size_t)c * 8192;
  floatx4 acc[8];
#pragma unroll
  for (int mi = 0; mi < 8; ++mi) acc[mi] = (floatx4){0.f, 0.f, 0.f, 0.f};
#pragma unroll
  for (int kk = 0; kk < 4; ++kk) {
    bf16x8 b0 = *(const bf16x8*)(LtC + (w8 * 16 + mh) * 128 + kk * 32 + quad * 8);
#pragma unroll
    for (int mi = 0; mi < 8; ++mi) {
      bf16x8 af = *(bf16x8*)&Y[(mi * 16 + mh) * 136 + kk * 32 + quad * 8];
      acc[mi] = __builtin_amdgcn_mfma_f32_16x16x32_bf16(af, b0, acc[mi], 0, 0, 0);
    }
  }
#pragma unroll
  for (int kk = 0; kk < 2; ++kk) {
    bf16x8 v0 = *(const bf16x8*)(VtC + (w8 * 16 + mh) * 64 + kk * 32 + quad * 8);
#pragma unroll
    for (int mi = 0; mi < 8; ++mi) {
      bf16x8 ah = *(bf16x8*)&H[(mi * 16 + mh) * 136 + kk * 32 + quad * 8];
      bf16x8 al = *(bf16x8*)&H[(mi * 16 + mh) * 136 + 64 + kk * 32 + quad * 8];
      acc[mi] = __builtin_amdgcn_mfma_f32_16x16x32_bf16(ah, v0, acc[mi], 0, 0, 0);
      acc[mi] = __builtin_amdgcn_mfma_f32_16x16x32_bf16(al, v0, acc[mi], 0, 0, 0);
    }
  }
  // epilogue: u = GELU(s + D*y) — tanh-form GELU via exp2/rcp (max |err| ~3e-4)
  bf16 ub[8][4];
  int jcol = w8 * 16 + mh;
#pragma unroll
  for (int mi = 0; mi < 8; ++mi)
#pragma unroll
    for (int r = 0; r < 4; ++r) {
      int p = mi * 16 + quad * 4 + r;
      float y = (float)Y[p * 136 + jcol];
      float sv = fmaf(Dc, y, acc[mi][r]);
      float s3 = sv * sv * sv;
      float zz = 0.7978845608028654f * fmaf(0.044715f, s3, sv);
      float e = __builtin_amdgcn_exp2f(zz * 2.8853900817779268f);  // exp(2z)
      float th = 1.f - 2.f * __builtin_amdgcn_rcpf(e + 1.f);
      ub[mi][r] = (bf16)(0.5f * sv * (1.f + th));
    }
  __syncthreads();   // all Y/H reads complete
#pragma unroll
  for (int mi = 0; mi < 8; ++mi)
#pragma unroll
    for (int r = 0; r < 4; ++r) {
      int p = mi * 16 + quad * 4 + r;
      Y[p * 136 + jcol] = ub[mi][r];
    }
  __syncthreads();
  // coalesced writeout U[b][c][t]
  bf16* Uc = U + (size_t)(b * cC + c) * cT;
#pragma unroll
  for (int it = 0; it < 8; ++it) {
    int i4 = tid + it * 512;
    if (i4 < 4000) {
      int t = i4 * 4, p = t >> 7, j = t & 127;
      *(bf16x4*)(Uc + t) = *(bf16x4*)&Y[p * 136 + j];
    }
  }
}

// ---------------- gemm2: z = W_out @ u (+bias, GLU, +residual), U in [b][c][t] ----------------
// 1024 threads (16 waves), 64 tokens x ALL 512 outs. Each wave: 16 GLU pairs ->
// acc 32 regs/thread; explicit 1-deep W prefetch (w1n/w2n) hides L2 latency.
// ~90 regs total <= 128 -> 4 waves/SIMD (16 waves/CU, 1 block/CU).
__global__ __launch_bounds__(1024, 4)
void gemm2_kernel(const bf16* __restrict__ U, const bf16* __restrict__ Wb,
                  const float* __restrict__ b_out, const float* __restrict__ x,
                  float* __restrict__ out) {
  __shared__ __align__(16) bf16 Ut[64 * 264];
  int bx = blockIdx.x;        // 0..1999
  int tb = bx % 250, b = bx / 250;
  int t0 = tb * 64;
  int tid = threadIdx.x, lane = tid & 63, w = tid >> 6, quad = lane >> 4, mh = lane & 15;
  // stage: 1024 threads: c = tid&255, th = tid>>8 (0..3), each stages 16 t into Ut[t][c]
  {
    int c = tid & 255, th = tid >> 8;
    const bf16* src = U + (size_t)(b * cC + c) * cT + t0 + th * 16;
#pragma unroll
    for (int g = 0; g < 2; ++g) {
      bf16x8 v = *(const bf16x8*)(src + g * 8);
#pragma unroll
      for (int k = 0; k < 8; ++k) Ut[(th * 16 + g * 8 + k) * 264 + c] = v[k];
    }
  }
  __syncthreads();
  // wave w (0..15) owns GLU pairs o = w*16 .. w*16+15 (z1 rows) and +256 (z2 rows)
  const bf16* Wrow1 = Wb + (size_t)(w * 16 + mh) * 256;
  const bf16* Wrow2 = Wb + (size_t)(w * 16 + 256 + mh) * 256;
  floatx4 a1[4], a2[4];
#pragma unroll
  for (int tt = 0; tt < 4; ++tt) {
    a1[tt] = (floatx4){0.f, 0.f, 0.f, 0.f};
    a2[tt] = (floatx4){0.f, 0.f, 0.f, 0.f};
  }
  int ko0 = quad * 8;
  bf16x8 w1c = *(const bf16x8*)(Wrow1 + ko0);
  bf16x8 w2c = *(const bf16x8*)(Wrow2 + ko0);
#pragma unroll
  for (int kk = 0; kk < 8; ++kk) {
    int ko = kk * 32 + quad * 8;
    bf16x8 w1n, w2n;
    if (kk < 7) {                       // prefetch next K-slice while MFMAing this one
      w1n = *(const bf16x8*)(Wrow1 + ko + 32);
      w2n = *(const bf16x8*)(Wrow2 + ko + 32);
    }
#pragma unroll
    for (int tt = 0; tt < 4; ++tt) {
      bf16x8 uf = *(bf16x8*)&Ut[(tt * 16 + mh) * 264 + ko];
      a1[tt] = __builtin_amdgcn_mfma_f32_16x16x32_bf16(w1c, uf, a1[tt], 0, 0, 0);
      a2[tt] = __builtin_amdgcn_mfma_f32_16x16x32_bf16(w2c, uf, a2[tt], 0, 0, 0);
    }
    if (kk < 7) { w1c = w1n; w2c = w2n; }
  }
#pragma unroll
  for (int tt = 0; tt < 4; ++tt)
#pragma unroll
    for (int r = 0; r < 4; ++r) {
      int o = w * 16 + quad * 4 + r;
      int t = t0 + tt * 16 + mh;
      float z1 = a1[tt][r] + b_out[o];
      float z2 = a2[tt][r] + b_out[o + 256];
      float sg = fast_sigmoid(z2);
      size_t idx = (size_t)(b * cC + o) * cT + t;
      out[idx] = x[idx] + z1 * sg;
    }
}

extern "C" void kernel_launch(void* const* d_in, const int* in_sizes, int n_in,
                              void* d_out, int out_size, void* d_ws, size_t ws_size,
                              hipStream_t stream) {
  const float* x          = (const float*)d_in[0];
  const float* gamma      = (const float*)d_in[1];
  const float* beta       = (const float*)d_in[2];
  const float* prelu_w    = (const float*)d_in[3];
  const float* log_dt     = (const float*)d_in[4];
  const float* log_A_real = (const float*)d_in[5];
  const float* A_imag     = (const float*)d_in[6];
  const float* C_re       = (const float*)d_in[7];
  const float* C_im       = (const float*)d_in[8];
  const float* Dp         = (const float*)d_in[9];
  const float* W_out      = (const float*)d_in[10];
  const float* b_out      = (const float*)d_in[11];
  float* out = (float*)d_out;
  char* ws = (char*)d_ws;

  float* meanp = (float*)(ws + kMean);
  float* rstdp = (float*)(ws + kRstd);
  float* wlr   = (float*)(ws + kWlr);
  float* wli   = (float*)(ws + kWli);
  bf16*  Wb    = (bf16*)(ws + kWb);
  bf16*  Lt    = (bf16*)(ws + kLt);
  bf16*  Et    = (bf16*)(ws + kEt);
  bf16*  Vt    = (bf16*)(ws + kVt);
  bf16*  U     = (bf16*)(ws + kU);

  prep_stats_kernel<<<1256, 512, 0, stream>>>(x, log_dt, log_A_real, A_imag, C_re,
                                              C_im, W_out, meanp, rstdp, wlr, wli,
                                              Wb, Lt, Et, Vt);
  scanM_kernel<<<cB * cC, 512, 0, stream>>>(x, meanp, rstdp, gamma, beta, prelu_w,
                                            Dp, wlr, wli, Lt, Et, Vt, U);
  gemm2_kernel<<<cB * (cT / 64), 1024, 0, stream>>>(U, Wb, b_out, x, out);
}